// Round 17
// baseline (32.676 us; speedup 1.0000x reference)
//
#include <hip/hip_runtime.h>
#include <hip/hip_bf16.h>

// B=32, IN_N=8192, POSE=64, M=8, NH=32, S2=256, HID=256, OUT_N=64
//
//  S[b,r][e]   = sum_{p<64} (CP[b, p*128+r] @ WC[p*128+r])[e],  r in [0,128), e=m1*8+m2
//              -> MFMA 16x16x32, 2 r's per wave (diag blocks), p half-split.
//              Stream: global_load_lds DMA into per-wave LDS 4-slot buffer,
//              counted vmcnt(4) pacing (R15 winner, byte-identical).
//              NEW: XCD-aware block swizzle — each XCD owns whole b-pairs, so its
//              4 MB CP slice fits its private L2 (L3-hit ~450cy -> L2-hit ~200cy).
//  F[r,e,q]    = sum_{hh<4} E_proj[r>>2, (r&3)*64+e, hh*64+q]
//  pooled[b,q] = (1/64) sum_j S[b,j] * F[j,q]   (fused pool, identical)
//  out[b,o,m1,m2] = sum_k (pooled[b,m1*8+k]+rel[m1*8+k]) * w_next[o,k,m2]

typedef short short8_t __attribute__((ext_vector_type(8)));
typedef float f32x4_t __attribute__((ext_vector_type(4)));
typedef int   int4_t  __attribute__((ext_vector_type(4)));

__device__ __forceinline__ short f2bf(float f) {
    union { float f; unsigned u; } v; v.f = f;
    unsigned r = v.u + 0x7FFFu + ((v.u >> 16) & 1u);   // RNE
    return (short)(r >> 16);
}

// packed f32x2 -> bf16x2 via HW instruction (no builtin on gfx950; m240)
__device__ __forceinline__ int cvt_pk(float x, float y) {
    int r;
    asm("v_cvt_pk_bf16_f32 %0, %1, %2" : "=v"(r) : "v"(x), "v"(y));
    return r;
}

// ---------- Kernel PREP: fused {WCf pack, E-fold} (identical since R6) ----------
__global__ void k_prep(const float* __restrict__ WC, short* __restrict__ WCf,
                       const float* __restrict__ E, float* __restrict__ F) {
    if (blockIdx.x < 256) {
        int t   = blockIdx.x * 256 + threadIdx.x;  // [0, 65536)
        int l   = t & 63;
        int pc  = (t >> 6) & 15;
        int rp  = t >> 10;
        int lhi = l >> 4;
        int j   = l & 15;
        int row = (pc * 4 + lhi) * 128 + rp * 2 + (j >> 3);
        const float* src = WC + ((size_t)row << 6) + (j & 7);
        short8_t o;
        #pragma unroll
        for (int k = 0; k < 8; ++k) o[k] = f2bf(src[k * 8]);
        ((short8_t*)WCf)[t] = o;
    } else {
        int idx = ((blockIdx.x - 256) * 256 + threadIdx.x) * 4;  // [0, 524288)
        int q   = idx & 63;
        int row = idx >> 6;
        int r   = row >> 6;
        int e   = row & 63;
        int nh  = r >> 2;
        int s2  = ((r & 3) << 6) + e;
        const float* base = E + (((size_t)nh * 256 + s2) << 8) + q;
        float4 s0 = *(const float4*)(base);
        float4 s1 = *(const float4*)(base + 64);
        float4 s2v = *(const float4*)(base + 128);
        float4 s3 = *(const float4*)(base + 192);
        float4 o;
        o.x = s0.x + s1.x + s2v.x + s3.x;
        o.y = s0.y + s1.y + s2v.y + s3.y;
        o.z = s0.z + s1.z + s2v.z + s3.z;
        o.w = s0.w + s1.w + s2v.w + s3.w;
        *(float4*)(F + idx) = o;
    }
}

// ---------- Kernel BC: gll-staged stream + MFMA + fused pool (R15) + XCD swizzle ----------
// launched as 1D grid of 512; decoded so XCD x runs bq = x (round 1) / x+8 (round 2):
// all 32 gx-blocks of one bq land on ONE XCD -> its 4 MB CP slice is L2-resident.
__global__ void __launch_bounds__(512, 4)
k_bc(const float* __restrict__ CP, const short* __restrict__ WCf,
     const float* __restrict__ F, float* __restrict__ P) {
    int f   = blockIdx.x;            // [0,512), dispatch order; XCD = f & 7 (round-robin)
    int xcd = f & 7;
    int qq  = f >> 3;                // [0,64)
    int gy  = xcd + ((qq >> 5) << 3);   // bq in [0,16): XCD-local
    int gx  = qq & 31;               // [0,32)

    int half = gx & 1;
    int rpg  = gx >> 1;              // [0,16)
    int b0   = gy * 2;
    int w = threadIdx.x >> 6;        // [0,8)
    int l = threadIdx.x & 63;
    int b_loc  = w & 1;
    int rp_loc = w >> 1;             // [0,4)
    int rp = rpg * 4 + rp_loc;       // [0,64)
    int r0 = rp * 2;
    int b  = b0 + b_loc;

    int i16   = l & 15;
    int r_sel = i16 >> 3;
    int m1    = i16 & 7;
    int lhi   = l >> 4;              // [0,4)

    __shared__ float gbuf[8][2048];  // 64 KB: per-wave staging (2 bufs x 2 chunks)
    __shared__ float Stile[2][512];  // [b_loc][j_loc]
    __shared__ float redp[8][2][64]; // [wave][b_loc][q]

    const float* cp_base = CP + ((size_t)b << 19) + ((size_t)(r0 + r_sel) << 6) + m1 * 8;
    const short8_t* wf   = (const short8_t*)WCf + (size_t)rp * 1024 + (half * 8) * 64 + l;

    // Preload ALL 8 B-fragments and force materialization BEFORE gll issues.
    short8_t wr0 = wf[0 * 64], wr1 = wf[1 * 64], wr2 = wf[2 * 64], wr3 = wf[3 * 64];
    short8_t wr4 = wf[4 * 64], wr5 = wf[5 * 64], wr6 = wf[6 * 64], wr7 = wf[7 * 64];
    asm volatile("" :: "v"(wr0), "v"(wr1), "v"(wr2), "v"(wr3),
                       "v"(wr4), "v"(wr5), "v"(wr6), "v"(wr7));
    asm volatile("s_waitcnt vmcnt(0)" ::: "memory");
    __builtin_amdgcn_sched_barrier(0);

    int wu = __builtin_amdgcn_readfirstlane(w);      // wave-uniform
    float* gb = &gbuf[wu][0];

    const float* pbase = cp_base + (((size_t)(half * 8) * 4 + lhi) << 13);
    #define CPA(c) (pbase + ((size_t)((c) * 4) << 13))

    // DMA chunk c into floats [off, off+512): lane i's 16B lands at base + i*16.
    #define ISSUE(c, off) do {                                                        \
        __builtin_amdgcn_global_load_lds((const void*)(CPA(c)),                       \
                                         (void*)(gb + (off)), 16, 0, 0);              \
        __builtin_amdgcn_global_load_lds((const void*)(CPA(c) + 4),                   \
                                         (void*)(gb + (off) + 256), 16, 0, 0);        \
    } while (0)

    #define WAITVM(N) do {                                                            \
        asm volatile("s_waitcnt vmcnt(" #N ")" ::: "memory");                         \
        __builtin_amdgcn_sched_barrier(0);                                            \
    } while (0)

    f32x4_t acc0 = {0.f, 0.f, 0.f, 0.f};
    f32x4_t acc1 = {0.f, 0.f, 0.f, 0.f};

    #define COMPUTE(off, wfr, accX) do {                                              \
        float4 x0 = *(const float4*)(gb + (off) + (size_t)l * 4);                     \
        float4 x1 = *(const float4*)(gb + (off) + 256 + (size_t)l * 4);               \
        int4_t ai;                                                                    \
        ai[0] = cvt_pk(x0.x, x0.y); ai[1] = cvt_pk(x0.z, x0.w);                       \
        ai[2] = cvt_pk(x1.x, x1.y); ai[3] = cvt_pk(x1.z, x1.w);                       \
        accX = __builtin_amdgcn_mfma_f32_16x16x32_bf16(                               \
            __builtin_bit_cast(short8_t, ai), wfr, accX, 0, 0, 0);                    \
    } while (0)

    ISSUE(0, 0);    ISSUE(1, 512);      // buf0  (vm outstanding: 4)
    ISSUE(2, 1024); ISSUE(3, 1536);     // buf1  (8)
    WAITVM(4);                          // buf0 ready
    COMPUTE(0, wr0, acc0); COMPUTE(512, wr1, acc1);
    __builtin_amdgcn_sched_barrier(0);
    ISSUE(4, 0);    ISSUE(5, 512);      // refill buf0 (8)
    WAITVM(4);                          // buf1 ready
    COMPUTE(1024, wr2, acc0); COMPUTE(1536, wr3, acc1);
    __builtin_amdgcn_sched_barrier(0);
    ISSUE(6, 1024); ISSUE(7, 1536);     // refill buf1 (8)
    WAITVM(4);                          // buf0' ready
    COMPUTE(0, wr4, acc0); COMPUTE(512, wr5, acc1);
    WAITVM(0);                          // buf1' ready
    COMPUTE(1024, wr6, acc0); COMPUTE(1536, wr7, acc1);

    #undef COMPUTE
    #undef WAITVM
    #undef ISSUE
    #undef CPA

    f32x4_t acc;
    #pragma unroll
    for (int v = 0; v < 4; ++v) acc[v] = acc0[v] + acc1[v];

    // C/D layout (m89-verified): col = lane&15, row = (lane>>4)*4 + reg
    int col = i16;
    #pragma unroll
    for (int v = 0; v < 4; ++v) {
        int row = lhi * 4 + v;
        if (row < 8 && col < 8)
            Stile[b_loc][rp_loc * 128 + row * 8 + col] = acc[v];
        else if (row >= 8 && col >= 8)
            Stile[b_loc][rp_loc * 128 + 64 + (row - 8) * 8 + (col - 8)] = acc[v];
    }
    __syncthreads();

    // Pool phase (identical to R12/R15): wave w covers jl in [w*64, w*64+64).
    int g  = l >> 4;
    int ql = l & 15;
    const float* Fb = F + (((size_t)(rpg * 512 + w * 64 + g)) << 6) + ql * 4;
    f32x4_t p0 = {0.f, 0.f, 0.f, 0.f};
    f32x4_t p1 = {0.f, 0.f, 0.f, 0.f};
    #pragma unroll 4
    for (int s = 0; s < 16; ++s) {
        int jl = w * 64 + s * 4 + g;
        float4 fv = *(const float4*)(Fb + ((size_t)(s * 4) << 6));
        float s0 = Stile[0][jl];
        float s1 = Stile[1][jl];
        p0[0] += s0 * fv.x; p0[1] += s0 * fv.y; p0[2] += s0 * fv.z; p0[3] += s0 * fv.w;
        p1[0] += s1 * fv.x; p1[1] += s1 * fv.y; p1[2] += s1 * fv.z; p1[3] += s1 * fv.w;
    }
    #pragma unroll
    for (int c = 0; c < 4; ++c) {
        p0[c] += __shfl_xor(p0[c], 16, 64);
        p0[c] += __shfl_xor(p0[c], 32, 64);
        p1[c] += __shfl_xor(p1[c], 16, 64);
        p1[c] += __shfl_xor(p1[c], 32, 64);
    }
    if (l < 16) {
        *(f32x4_t*)(&redp[w][0][ql * 4]) = p0;
        *(f32x4_t*)(&redp[w][1][ql * 4]) = p1;
    }
    __syncthreads();

    if (threadIdx.x < 128) {
        int bb = threadIdx.x >> 6;
        int q  = threadIdx.x & 63;
        float s = 0.f;
        #pragma unroll
        for (int ww = 0; ww < 8; ++ww) s += redp[ww][bb][q];
        P[((size_t)((b0 + bb) * 32 + gx) << 6) + q] = s;
    }
}

// ---------- Kernel FINAL (identical to R12/R15) ----------
__global__ void k_final(const float* __restrict__ P, const float* __restrict__ rel,
                        const float* __restrict__ WN, float* __restrict__ out) {
    int b  = blockIdx.x;
    int t  = threadIdx.x;
    int q    = t & 63;
    int sgrp = t >> 6;               // [0,4): 8 slots each
    const float* Pb = P + ((size_t)(b * 32) << 6);
    float s = 0.f;
    #pragma unroll
    for (int c = sgrp * 8; c < sgrp * 8 + 8; ++c)
        s += Pb[((size_t)c << 6) + q];
    __shared__ float red[4][64];
    red[sgrp][q] = s;
    __syncthreads();
    __shared__ float pool_s[64];
    if (t < 64) {
        pool_s[t] = (red[0][t] + red[1][t] + red[2][t] + red[3][t]) * (1.0f / 64.0f)
                    + rel[t];
    }
    __syncthreads();
    #pragma unroll
    for (int idx = t; idx < 4096; idx += 256) {
        int o = idx >> 6;
        int e = idx & 63;
        int m1 = e >> 3, m2 = e & 7;
        float a = 0.f;
        #pragma unroll
        for (int k = 0; k < 8; ++k)
            a += pool_s[m1 * 8 + k] * WN[o * 64 + k * 8 + m2];
        out[((size_t)b << 12) + idx] = a;
    }
}

extern "C" void kernel_launch(void* const* d_in, const int* in_sizes, int n_in,
                              void* d_out, int out_size, void* d_ws, size_t ws_size,
                              hipStream_t stream) {
    const float* current_pose = (const float*)d_in[0];  // (32, 8192, 64)
    const float* w_current    = (const float*)d_in[1];  // (1,1,8192,8,8)
    const float* w_next       = (const float*)d_in[2];  // (64,8,8)
    const float* E_proj       = (const float*)d_in[3];  // (32,256,256)
    const float* rel_embedd   = (const float*)d_in[4];  // (1,1,64)
    float* out = (float*)d_out;                         // (32,1,64,64)

    char* ws = (char*)d_ws;
    float* F   = (float*)(ws);                    // 2 MiB
    short* WCf = (short*)(ws + (2u << 20));       // 1 MiB
    float* P   = (float*)(ws + (3u << 20));       // 256 KiB (32 x 32 x 64)

    // PREP: WCf pack (256 blocks) + E fold (512 blocks)
    k_prep<<<dim3(768), dim3(256), 0, stream>>>(w_current, WCf, E_proj, F);
    // BC: R15 stream + fused pool, XCD-swizzled (1D grid, decoded in-kernel)
    k_bc<<<dim3(512), dim3(512), 0, stream>>>(current_pose, WCf, F, P);
    // FINAL
    k_final<<<dim3(32), dim3(256), 0, stream>>>(P, rel_embedd, w_next, out);
}

// Round 18
// 27.311 us; speedup vs baseline: 1.1964x; 1.1964x over previous
//
#include <hip/hip_runtime.h>
#include <hip/hip_bf16.h>

// B=32, IN_N=8192, POSE=64, M=8, NH=32, S2=256, HID=256, OUT_N=64
//
//  S[b,r][e]   = sum_{p<64} (CP[b, p*128+r] @ WC[p*128+r])[e],  r in [0,128), e=m1*8+m2
//              -> MFMA 16x16x32, 2 r's per wave (diag blocks), p half-split.
//              Stream: global_load_lds DMA into per-wave LDS 4-slot buffer,
//              counted vmcnt(4) pacing (R15 winner, byte-identical).
//  F[r,e,q]    = sum_{hh<4} E_proj[r>>2, (r&3)*64+e, hh*64+q]
//  pooled[b,q] = (1/64) sum_j S[b,j] * F[j,q]   (fused pool, identical to R15)
//  out[b,o,m1,m2] = sum_k (pooled[b,m1*8+k]+rel[m1*8+k]) * w_next[o,k,m2]
//  FINAL widened to (32,4) blocks: reduction duplicated per o-chunk (8KB L2-hot),
//  epilogue split 4-way -> 128 blocks instead of 32 (tail TLP x4).

typedef short short8_t __attribute__((ext_vector_type(8)));
typedef float f32x4_t __attribute__((ext_vector_type(4)));
typedef int   int4_t  __attribute__((ext_vector_type(4)));

__device__ __forceinline__ short f2bf(float f) {
    union { float f; unsigned u; } v; v.f = f;
    unsigned r = v.u + 0x7FFFu + ((v.u >> 16) & 1u);   // RNE
    return (short)(r >> 16);
}

// packed f32x2 -> bf16x2 via HW instruction (no builtin on gfx950; m240)
__device__ __forceinline__ int cvt_pk(float x, float y) {
    int r;
    asm("v_cvt_pk_bf16_f32 %0, %1, %2" : "=v"(r) : "v"(x), "v"(y));
    return r;
}

// ---------- Kernel PREP: fused {WCf pack, E-fold} (identical since R6) ----------
__global__ void k_prep(const float* __restrict__ WC, short* __restrict__ WCf,
                       const float* __restrict__ E, float* __restrict__ F) {
    if (blockIdx.x < 256) {
        int t   = blockIdx.x * 256 + threadIdx.x;  // [0, 65536)
        int l   = t & 63;
        int pc  = (t >> 6) & 15;
        int rp  = t >> 10;
        int lhi = l >> 4;
        int j   = l & 15;
        int row = (pc * 4 + lhi) * 128 + rp * 2 + (j >> 3);
        const float* src = WC + ((size_t)row << 6) + (j & 7);
        short8_t o;
        #pragma unroll
        for (int k = 0; k < 8; ++k) o[k] = f2bf(src[k * 8]);
        ((short8_t*)WCf)[t] = o;
    } else {
        int idx = ((blockIdx.x - 256) * 256 + threadIdx.x) * 4;  // [0, 524288)
        int q   = idx & 63;
        int row = idx >> 6;
        int r   = row >> 6;
        int e   = row & 63;
        int nh  = r >> 2;
        int s2  = ((r & 3) << 6) + e;
        const float* base = E + (((size_t)nh * 256 + s2) << 8) + q;
        float4 s0 = *(const float4*)(base);
        float4 s1 = *(const float4*)(base + 64);
        float4 s2v = *(const float4*)(base + 128);
        float4 s3 = *(const float4*)(base + 192);
        float4 o;
        o.x = s0.x + s1.x + s2v.x + s3.x;
        o.y = s0.y + s1.y + s2v.y + s3.y;
        o.z = s0.z + s1.z + s2v.z + s3.z;
        o.w = s0.w + s1.w + s2v.w + s3.w;
        *(float4*)(F + idx) = o;
    }
}

// ---------- Kernel BC: gll-staged stream + MFMA + fused pool (byte-identical R15) ----------
// grid (32, 16): gx = rpg*2+half, gy = bq (b0 = bq*2). 512 threads = 8 waves.
__global__ void __launch_bounds__(512, 4)
k_bc(const float* __restrict__ CP, const short* __restrict__ WCf,
     const float* __restrict__ F, float* __restrict__ P) {
    int gx   = blockIdx.x;
    int half = gx & 1;
    int rpg  = gx >> 1;              // [0,16)
    int b0   = blockIdx.y * 2;
    int w = threadIdx.x >> 6;        // [0,8)
    int l = threadIdx.x & 63;
    int b_loc  = w & 1;
    int rp_loc = w >> 1;             // [0,4)
    int rp = rpg * 4 + rp_loc;       // [0,64)
    int r0 = rp * 2;
    int b  = b0 + b_loc;

    int i16   = l & 15;
    int r_sel = i16 >> 3;
    int m1    = i16 & 7;
    int lhi   = l >> 4;              // [0,4)

    __shared__ float gbuf[8][2048];  // 64 KB: per-wave staging (2 bufs x 2 chunks)
    __shared__ float Stile[2][512];  // [b_loc][j_loc]
    __shared__ float redp[8][2][64]; // [wave][b_loc][q]

    const float* cp_base = CP + ((size_t)b << 19) + ((size_t)(r0 + r_sel) << 6) + m1 * 8;
    const short8_t* wf   = (const short8_t*)WCf + (size_t)rp * 1024 + (half * 8) * 64 + l;

    // Preload ALL 8 B-fragments and force materialization BEFORE gll issues.
    short8_t wr0 = wf[0 * 64], wr1 = wf[1 * 64], wr2 = wf[2 * 64], wr3 = wf[3 * 64];
    short8_t wr4 = wf[4 * 64], wr5 = wf[5 * 64], wr6 = wf[6 * 64], wr7 = wf[7 * 64];
    asm volatile("" :: "v"(wr0), "v"(wr1), "v"(wr2), "v"(wr3),
                       "v"(wr4), "v"(wr5), "v"(wr6), "v"(wr7));
    asm volatile("s_waitcnt vmcnt(0)" ::: "memory");
    __builtin_amdgcn_sched_barrier(0);

    int wu = __builtin_amdgcn_readfirstlane(w);      // wave-uniform
    float* gb = &gbuf[wu][0];

    const float* pbase = cp_base + (((size_t)(half * 8) * 4 + lhi) << 13);
    #define CPA(c) (pbase + ((size_t)((c) * 4) << 13))

    #define ISSUE(c, off) do {                                                        \
        __builtin_amdgcn_global_load_lds((const void*)(CPA(c)),                       \
                                         (void*)(gb + (off)), 16, 0, 0);              \
        __builtin_amdgcn_global_load_lds((const void*)(CPA(c) + 4),                   \
                                         (void*)(gb + (off) + 256), 16, 0, 0);        \
    } while (0)

    #define WAITVM(N) do {                                                            \
        asm volatile("s_waitcnt vmcnt(" #N ")" ::: "memory");                         \
        __builtin_amdgcn_sched_barrier(0);                                            \
    } while (0)

    f32x4_t acc0 = {0.f, 0.f, 0.f, 0.f};
    f32x4_t acc1 = {0.f, 0.f, 0.f, 0.f};

    #define COMPUTE(off, wfr, accX) do {                                              \
        float4 x0 = *(const float4*)(gb + (off) + (size_t)l * 4);                     \
        float4 x1 = *(const float4*)(gb + (off) + 256 + (size_t)l * 4);               \
        int4_t ai;                                                                    \
        ai[0] = cvt_pk(x0.x, x0.y); ai[1] = cvt_pk(x0.z, x0.w);                       \
        ai[2] = cvt_pk(x1.x, x1.y); ai[3] = cvt_pk(x1.z, x1.w);                       \
        accX = __builtin_amdgcn_mfma_f32_16x16x32_bf16(                               \
            __builtin_bit_cast(short8_t, ai), wfr, accX, 0, 0, 0);                    \
    } while (0)

    ISSUE(0, 0);    ISSUE(1, 512);      // buf0  (vm outstanding: 4)
    ISSUE(2, 1024); ISSUE(3, 1536);     // buf1  (8)
    WAITVM(4);                          // buf0 ready
    COMPUTE(0, wr0, acc0); COMPUTE(512, wr1, acc1);
    __builtin_amdgcn_sched_barrier(0);
    ISSUE(4, 0);    ISSUE(5, 512);      // refill buf0 (8)
    WAITVM(4);                          // buf1 ready
    COMPUTE(1024, wr2, acc0); COMPUTE(1536, wr3, acc1);
    __builtin_amdgcn_sched_barrier(0);
    ISSUE(6, 1024); ISSUE(7, 1536);     // refill buf1 (8)
    WAITVM(4);                          // buf0' ready
    COMPUTE(0, wr4, acc0); COMPUTE(512, wr5, acc1);
    WAITVM(0);                          // buf1' ready
    COMPUTE(1024, wr6, acc0); COMPUTE(1536, wr7, acc1);

    #undef COMPUTE
    #undef WAITVM
    #undef ISSUE
    #undef CPA

    f32x4_t acc;
    #pragma unroll
    for (int v = 0; v < 4; ++v) acc[v] = acc0[v] + acc1[v];

    // C/D layout (m89-verified): col = lane&15, row = (lane>>4)*4 + reg
    int col = i16;
    #pragma unroll
    for (int v = 0; v < 4; ++v) {
        int row = lhi * 4 + v;
        if (row < 8 && col < 8)
            Stile[b_loc][rp_loc * 128 + row * 8 + col] = acc[v];
        else if (row >= 8 && col >= 8)
            Stile[b_loc][rp_loc * 128 + 64 + (row - 8) * 8 + (col - 8)] = acc[v];
    }
    __syncthreads();

    // Pool phase (identical to R15): wave w covers jl in [w*64, w*64+64).
    int g  = l >> 4;
    int ql = l & 15;
    const float* Fb = F + (((size_t)(rpg * 512 + w * 64 + g)) << 6) + ql * 4;
    f32x4_t p0 = {0.f, 0.f, 0.f, 0.f};
    f32x4_t p1 = {0.f, 0.f, 0.f, 0.f};
    #pragma unroll 4
    for (int s = 0; s < 16; ++s) {
        int jl = w * 64 + s * 4 + g;
        float4 fv = *(const float4*)(Fb + ((size_t)(s * 4) << 6));
        float s0 = Stile[0][jl];
        float s1 = Stile[1][jl];
        p0[0] += s0 * fv.x; p0[1] += s0 * fv.y; p0[2] += s0 * fv.z; p0[3] += s0 * fv.w;
        p1[0] += s1 * fv.x; p1[1] += s1 * fv.y; p1[2] += s1 * fv.z; p1[3] += s1 * fv.w;
    }
    #pragma unroll
    for (int c = 0; c < 4; ++c) {
        p0[c] += __shfl_xor(p0[c], 16, 64);
        p0[c] += __shfl_xor(p0[c], 32, 64);
        p1[c] += __shfl_xor(p1[c], 16, 64);
        p1[c] += __shfl_xor(p1[c], 32, 64);
    }
    if (l < 16) {
        *(f32x4_t*)(&redp[w][0][ql * 4]) = p0;
        *(f32x4_t*)(&redp[w][1][ql * 4]) = p1;
    }
    __syncthreads();

    if (threadIdx.x < 128) {
        int bb = threadIdx.x >> 6;
        int q  = threadIdx.x & 63;
        float s = 0.f;
        #pragma unroll
        for (int ww = 0; ww < 8; ++ww) s += redp[ww][bb][q];
        P[((size_t)((b0 + bb) * 32 + gx) << 6) + q] = s;
    }
}

// ---------- Kernel FINAL: widened to (32,4) — epilogue split 4-way ----------
__global__ void k_final(const float* __restrict__ P, const float* __restrict__ rel,
                        const float* __restrict__ WN, float* __restrict__ out) {
    int b  = blockIdx.x;
    int oc = blockIdx.y;             // [0,4): 16 o's each
    int t  = threadIdx.x;
    int q    = t & 63;
    int sgrp = t >> 6;               // [0,4): 8 slots each
    const float* Pb = P + ((size_t)(b * 32) << 6);
    float s = 0.f;
    #pragma unroll
    for (int c = sgrp * 8; c < sgrp * 8 + 8; ++c)
        s += Pb[((size_t)c << 6) + q];
    __shared__ float red[4][64];
    red[sgrp][q] = s;
    __syncthreads();
    __shared__ float pool_s[64];
    if (t < 64) {
        pool_s[t] = (red[0][t] + red[1][t] + red[2][t] + red[3][t]) * (1.0f / 64.0f)
                    + rel[t];
    }
    __syncthreads();
    #pragma unroll
    for (int idx = t; idx < 1024; idx += 256) {
        int o = oc * 16 + (idx >> 6);
        int e = idx & 63;
        int m1 = e >> 3, m2 = e & 7;
        float a = 0.f;
        #pragma unroll
        for (int k = 0; k < 8; ++k)
            a += pool_s[m1 * 8 + k] * WN[o * 64 + k * 8 + m2];
        out[((size_t)b << 12) + o * 64 + e] = a;
    }
}

extern "C" void kernel_launch(void* const* d_in, const int* in_sizes, int n_in,
                              void* d_out, int out_size, void* d_ws, size_t ws_size,
                              hipStream_t stream) {
    const float* current_pose = (const float*)d_in[0];  // (32, 8192, 64)
    const float* w_current    = (const float*)d_in[1];  // (1,1,8192,8,8)
    const float* w_next       = (const float*)d_in[2];  // (64,8,8)
    const float* E_proj       = (const float*)d_in[3];  // (32,256,256)
    const float* rel_embedd   = (const float*)d_in[4];  // (1,1,64)
    float* out = (float*)d_out;                         // (32,1,64,64)

    char* ws = (char*)d_ws;
    float* F   = (float*)(ws);                    // 2 MiB
    short* WCf = (short*)(ws + (2u << 20));       // 1 MiB
    float* P   = (float*)(ws + (3u << 20));       // 256 KiB (32 x 32 x 64)

    // PREP: WCf pack (256 blocks) + E fold (512 blocks)
    k_prep<<<dim3(768), dim3(256), 0, stream>>>(w_current, WCf, E_proj, F);
    // BC: R15 stream + fused pool (byte-identical)
    k_bc<<<dim3(32, 16), dim3(512), 0, stream>>>(current_pose, WCf, F, P);
    // FINAL: 128 blocks (4x tail TLP)
    k_final<<<dim3(32, 4), dim3(256), 0, stream>>>(P, rel_embedd, w_next, out);
}